// Round 7
// baseline (216.636 us; speedup 1.0000x reference)
//
#include <hip/hip_runtime.h>
#include <hip/hip_bf16.h>

typedef __attribute__((ext_vector_type(8))) short short8;
typedef __attribute__((ext_vector_type(4))) float floatx4;

constexpr float LN_EPS = 1e-5f;
constexpr float NEG_INF_V = -1e30f;

// 20 KB device-global: pre-swizzled C^T bf16 hi/lo fragments + w0-column tile.
// hi frags 0-7: [0..4095]; lo frags 0-7: [4096..8191];
// tile-4 (w0 col) hi kk=0/1: [8192..9215]; lo kk=0/1: [9216..10239].
__device__ unsigned short g_wsC[10240];

// ---- bf16 helpers ----
// software RNE (prep kernel only; == HW RNE)
__device__ __forceinline__ unsigned short bf16hi_sw(float x) {
    unsigned int u = __builtin_bit_cast(unsigned int, x);
    u += 0x7FFFu + ((u >> 16) & 1u);
    return (unsigned short)(u >> 16);
}
__device__ __forceinline__ float bf16f(unsigned short h) {
    unsigned int u = ((unsigned int)h) << 16;
    return __builtin_bit_cast(float, u);
}
// HW RNE packed convert; u32: [15:0]=bf16(a), [31:16]=bf16(b)
__device__ __forceinline__ unsigned int pk2(float a, float b) {
    float2 f2; f2.x = a; f2.y = b;
    __hip_bfloat162 h2 = __float22bfloat162_rn(f2);
    unsigned int u;
    __builtin_memcpy(&u, &h2, sizeof(u));
    return u;
}
// hi/lo split of a pair: lo captures hi's rounding residual (error ~2^-17)
__device__ __forceinline__ void splitpk(float a, float b,
                                        unsigned int& H, unsigned int& L) {
    H = pk2(a, b);
    const float ha = __builtin_bit_cast(float, H << 16);
    const float hb = __builtin_bit_cast(float, H & 0xFFFF0000u);
    L = pk2(a - ha, b - hb);
}

// byte-perm packs: lo16(A)|lo16(B)<<16  /  hi16(A)|hi16(B)<<16
__device__ __forceinline__ unsigned int permlo(unsigned int A, unsigned int B) {
    return __builtin_amdgcn_perm(B, A, 0x05040100u);
}
__device__ __forceinline__ unsigned int permhi(unsigned int A, unsigned int B) {
    return __builtin_amdgcn_perm(B, A, 0x07060302u);
}

// ---- DPP rotate-reduce over 16-lane rows (VALU pipe, zero DS ops) ----
template<int CTRL>
__device__ __forceinline__ float dppadd(float v) {
    int t = __builtin_amdgcn_update_dpp(0, __builtin_bit_cast(int, v),
                                        CTRL, 0xF, 0xF, true);
    return v + __builtin_bit_cast(float, t);
}
template<int CTRL>
__device__ __forceinline__ float dppmax(float v) {
    int t = __builtin_amdgcn_update_dpp(0, __builtin_bit_cast(int, v),
                                        CTRL, 0xF, 0xF, true);
    return fmaxf(v, __builtin_bit_cast(float, t));
}
__device__ __forceinline__ float rsum16(float v) {
    v = dppadd<0x121>(v); v = dppadd<0x122>(v);
    v = dppadd<0x124>(v); v = dppadd<0x128>(v);
    return v;
}
__device__ __forceinline__ float rmax16(float v) {
    v = dppmax<0x121>(v); v = dppmax<0x122>(v);
    v = dppmax<0x124>(v); v = dppmax<0x128>(v);
    return v;
}

// XOR-swizzled 64x64 bf16 LDS layout (sFi/sFt): group g of row r at g ^ (r&7)
__device__ __forceinline__ int eoff(int r, int c) {
    return r * 64 + ((((c >> 3) ^ r) & 7) << 3) + (c & 7);
}
__device__ __forceinline__ int goff(int r, int g) {
    return r * 64 + (((g ^ r) & 7) << 3);
}
// wave-private 16x32 medium half (fiC): swizzle by row>>2 (quad)
__device__ __forceinline__ int moff(int r, int c) {
    return r * 32 + ((((c >> 3) ^ (r >> 2)) & 3) << 3) + (c & 7);
}
// wave-private 16x64 alpha layout
__device__ __forceinline__ int aoff(int r, int c) {
    return r * 64 + ((((c >> 3) ^ (r >> 2)) & 7) << 3) + (c & 7);
}

// One-shot: C^T fragments + w0-column tile, bf16 hi/lo, MFMA B-frag order.
// Frag f=t*2+kk elem e = Ct[16t+(lane&15)][(kk*4+(lane>>4))*8+e] = corr[k][...].
// Tile-4 kk: col 64 = w0 (lane n==0), cols 65-79 = 0.
__global__ void prep_corr(const float* __restrict__ corr,
                          const float* __restrict__ lw) {
    const int tid  = threadIdx.x;   // 256
    const int lane = tid & 63;
    const int t    = tid >> 6;
    const int nn   = lane & 15;
    const int q    = lane >> 4;
    const int brow = 16 * t + nn;
    #pragma unroll
    for (int kk = 0; kk < 2; ++kk) {
        const int kbase = (kk * 4 + q) * 8;
        short8 H8, L8;
        #pragma unroll
        for (int e = 0; e < 8; ++e) {
            const float v = corr[(kbase + e) * 64 + brow];
            const unsigned short hh = bf16hi_sw(v);
            const unsigned short ll = bf16hi_sw(v - bf16f(hh));
            H8[e] = (short)hh;
            L8[e] = (short)ll;
        }
        const int idx = ((t * 2 + kk) * 64 + lane) * 8;
        *(short8*)&g_wsC[idx]        = H8;
        *(short8*)&g_wsC[4096 + idx] = L8;
    }
    if (t == 0) {   // tile-4: B[k][64+n] = (n==0) ? w0[k] : 0
        #pragma unroll
        for (int kk = 0; kk < 2; ++kk) {
            short8 H8, L8;
            #pragma unroll
            for (int e = 0; e < 8; ++e) {
                const float v = (nn == 0) ? lw[(kk * 4 + q) * 8 + e] : 0.0f;
                const unsigned short hh = bf16hi_sw(v);
                const unsigned short ll = bf16hi_sw(v - bf16f(hh));
                H8[e] = (short)hh;
                L8[e] = (short)ll;
            }
            const int idx = (kk * 64 + lane) * 8;
            *(short8*)&g_wsC[8192 + idx] = H8;
            *(short8*)&g_wsC[9216 + idx] = L8;
        }
    }
}

__global__ __launch_bounds__(256, 4)
void attn_mfma(const float* __restrict__ fi,
               const float* __restrict__ ln_g,
               const float* __restrict__ ln_b,
               const float* __restrict__ lw,
               const float* __restrict__ lb,
               float* __restrict__ out)
{
    // 8+8+8+16 KB = 40960 B -> 4 blocks/CU
    __shared__ __align__(16) unsigned short sFiH[4096], sFiL[4096]; // fi rows h/l
    __shared__ __align__(16) unsigned short sFtH[4096];             // fi^T rows, hi
    // sM: wave-private medium, 2048 shorts/wave.
    // fiC phase: half kh at [kh*1024]: hi [0..511], lo [512..1023].
    // alpha phase: 16x64 hi in [0..1023].
    __shared__ __align__(16) unsigned short sM[8192];

    const int tid  = threadIdx.x;
    const int lane = tid & 63;
    const int w    = tid >> 6;
    const int n    = lane & 15;
    const int quad = lane >> 4;
    const size_t blk = blockIdx.x;
    const int rw   = __builtin_amdgcn_readfirstlane(w);

    unsigned short* mW = &sM[w * 2048];

    // ---- staging: thread owns a 4x4 tile of fi: rows R..R+3, cols C..C+3 ----
    const int C = 4 * n;
    const int R = 4 * (tid >> 4);   // = 16w + 4*quad (wave-private rows)
    {
        const float* fb = fi + blk * 4096;
        float4 v[4];
        #pragma unroll
        for (int i = 0; i < 4; ++i)
            v[i] = *(const float4*)(fb + (R + i) * 64 + C);

        unsigned int H01[4], H23[4], L01[4], L23[4];
        #pragma unroll
        for (int i = 0; i < 4; ++i) {
            splitpk(v[i].x, v[i].y, H01[i], L01[i]);
            splitpk(v[i].z, v[i].w, H23[i], L23[i]);
        }
        #pragma unroll
        for (int i = 0; i < 4; ++i) {
            uint2 H = {H01[i], H23[i]};
            uint2 L = {L01[i], L23[i]};
            *(uint2*)&sFiH[eoff(R + i, C)] = H;
            *(uint2*)&sFiL[eoff(R + i, C)] = L;
        }
        // fi^T rows (hi only): col C+j holds fi[R..R+3][C+j], packed b64
        uint2 t0 = {permlo(H01[0], H01[1]), permlo(H01[2], H01[3])};
        uint2 t1 = {permhi(H01[0], H01[1]), permhi(H01[2], H01[3])};
        uint2 t2 = {permlo(H23[0], H23[1]), permlo(H23[2], H23[3])};
        uint2 t3 = {permhi(H23[0], H23[1]), permhi(H23[2], H23[3])};
        *(uint2*)&sFtH[eoff(C + 0, R)] = t0;
        *(uint2*)&sFtH[eoff(C + 1, R)] = t1;
        *(uint2*)&sFtH[eoff(C + 2, R)] = t2;
        *(uint2*)&sFtH[eoff(C + 3, R)] = t3;
    }

    const int arow = 16 * w + n;

    // ---- M1: fiC = fi @ C + d0 tile (A: own-wave sFi rows; B: g_wsC frags) ----
    short8 Ah[2], Al[2];
    #pragma unroll
    for (int kk = 0; kk < 2; ++kk) {
        Ah[kk] = *(const short8*)&sFiH[goff(arow, kk * 4 + quad)];
        Al[kk] = *(const short8*)&sFiL[goff(arow, kk * 4 + quad)];
    }
    floatx4 acc1[4];
    #pragma unroll
    for (int t = 0; t < 4; ++t) {
        floatx4 acc = {0.f, 0.f, 0.f, 0.f};
        #pragma unroll
        for (int kk = 0; kk < 2; ++kk) {
            const int f = t * 2 + kk;
            short8 bh = *(const short8*)&g_wsC[(f * 64 + lane) * 8];
            short8 bl = *(const short8*)&g_wsC[4096 + (f * 64 + lane) * 8];
            acc = __builtin_amdgcn_mfma_f32_16x16x32_bf16(Ah[kk], bh, acc, 0, 0, 0);
            acc = __builtin_amdgcn_mfma_f32_16x16x32_bf16(Al[kk], bh, acc, 0, 0, 0);
            acc = __builtin_amdgcn_mfma_f32_16x16x32_bf16(Ah[kk], bl, acc, 0, 0, 0);
        }
        acc1[t] = acc;
    }
    // tile-4: d0[row] = fi[row]·w0 lands in accd[reg] at lanes n==0
    floatx4 accd = {0.f, 0.f, 0.f, 0.f};
    #pragma unroll
    for (int kk = 0; kk < 2; ++kk) {
        short8 bh = *(const short8*)&g_wsC[8192 + (kk * 64 + lane) * 8];
        short8 bl = *(const short8*)&g_wsC[9216 + (kk * 64 + lane) * 8];
        accd = __builtin_amdgcn_mfma_f32_16x16x32_bf16(Ah[kk], bh, accd, 0, 0, 0);
        accd = __builtin_amdgcn_mfma_f32_16x16x32_bf16(Al[kk], bh, accd, 0, 0, 0);
        accd = __builtin_amdgcn_mfma_f32_16x16x32_bf16(Ah[kk], bl, accd, 0, 0, 0);
    }

    __syncthreads();   // single barrier: sFi/sFt staging visible to all waves

    // ---- M2: beta = fiC @ fi^T. Write BOTH K-halves of fiC into the medium,
    // read all 4 A-frags, then run all 24 MFMAs (one DS-latency stall). ----
    #pragma unroll
    for (int kh = 0; kh < 2; ++kh) {
        #pragma unroll
        for (int th = 0; th < 2; ++th) {
            const int t = 2 * kh + th;
            unsigned int H01, L01, H23, L23;
            splitpk(acc1[t][0], acc1[t][1], H01, L01);
            splitpk(acc1[t][2], acc1[t][3], H23, L23);
            const int c  = 16 * th + n;
            const int r0 = 4 * quad;
            unsigned short* m = &mW[kh * 1024];
            m[moff(r0 + 0, c)]       = (unsigned short)H01;
            m[moff(r0 + 1, c)]       = (unsigned short)(H01 >> 16);
            m[moff(r0 + 2, c)]       = (unsigned short)H23;
            m[moff(r0 + 3, c)]       = (unsigned short)(H23 >> 16);
            m[512 + moff(r0 + 0, c)] = (unsigned short)L01;
            m[512 + moff(r0 + 1, c)] = (unsigned short)(L01 >> 16);
            m[512 + moff(r0 + 2, c)] = (unsigned short)L23;
            m[512 + moff(r0 + 3, c)] = (unsigned short)(L23 >> 16);
        }
    }
    short8 PAh[2], PAl[2];
    #pragma unroll
    for (int kh = 0; kh < 2; ++kh) {
        PAh[kh] = *(const short8*)&mW[kh * 1024 + moff(n, quad * 8)];
        PAl[kh] = *(const short8*)&mW[kh * 1024 + 512 + moff(n, quad * 8)];
    }
    floatx4 acc2[4];
    #pragma unroll
    for (int t = 0; t < 4; ++t) acc2[t] = floatx4{0.f, 0.f, 0.f, 0.f};
    #pragma unroll
    for (int kh = 0; kh < 2; ++kh) {
        #pragma unroll
        for (int t = 0; t < 4; ++t) {
            const int brow = 16 * t + n;
            short8 bh = *(const short8*)&sFiH[goff(brow, kh * 4 + quad)];
            short8 bl = *(const short8*)&sFiL[goff(brow, kh * 4 + quad)];
            acc2[t] = __builtin_amdgcn_mfma_f32_16x16x32_bf16(PAh[kh], bh, acc2[t], 0, 0, 0);
            acc2[t] = __builtin_amdgcn_mfma_f32_16x16x32_bf16(PAl[kh], bh, acc2[t], 0, 0, 0);
            acc2[t] = __builtin_amdgcn_mfma_f32_16x16x32_bf16(PAh[kh], bl, acc2[t], 0, 0, 0);
        }
    }

    // ---- masked softmax, UNNORMALIZED (LN is scale-invariant) ----
    // diag col == row  <=>  t == w (wave-uniform) && n == 4*quad+reg
    #pragma unroll
    for (int reg = 0; reg < 4; ++reg) {
        float x[4];
        #pragma unroll
        for (int t = 0; t < 4; ++t) x[t] = acc2[t][reg];
        #pragma unroll
        for (int t = 0; t < 4; ++t)
            if (t == rw)    // uniform branch: one cndmask survives
                x[t] = (n == 4 * quad + reg) ? NEG_INF_V : x[t];
        float m = fmaxf(fmaxf(x[0], x[1]), fmaxf(x[2], x[3]));
        m = rmax16(m);
        #pragma unroll
        for (int t = 0; t < 4; ++t) x[t] = __expf(x[t] - m);   // <= 1
        const unsigned int A01 = pk2(x[0], x[1]);
        const unsigned int A23 = pk2(x[2], x[3]);
        const int lr = quad * 4 + reg;          // local row within wave
        mW[aoff(lr, 0 + n)]  = (unsigned short)A01;
        mW[aoff(lr, 16 + n)] = (unsigned short)(A01 >> 16);
        mW[aoff(lr, 32 + n)] = (unsigned short)A23;
        mW[aoff(lr, 48 + n)] = (unsigned short)(A23 >> 16);
    }

    // ---- M3: vi_unnorm = exp(beta-m) @ fi (hi-only single pass) ----
    short8 AAh[2];
    #pragma unroll
    for (int kk = 0; kk < 2; ++kk)
        AAh[kk] = *(const short8*)&mW[aoff(n, (kk * 4 + quad) * 8)];
    floatx4 acc3[4];
    #pragma unroll
    for (int t = 0; t < 4; ++t) {
        floatx4 acc = {0.f, 0.f, 0.f, 0.f};
        const int brow = 16 * t + n;
        #pragma unroll
        for (int kk = 0; kk < 2; ++kk) {
            short8 bh = *(const short8*)&sFtH[goff(brow, kk * 4 + quad)];
            acc = __builtin_amdgcn_mfma_f32_16x16x32_bf16(AAh[kk], bh, acc, 0, 0, 0);
        }
        acc3[t] = acc;
    }

    // ---- LN + ReLU + final dot + sigmoid ----
    float gv[4], bv[4], w1v[4];
    #pragma unroll
    for (int t = 0; t < 4; ++t) {
        gv[t]  = ln_g[16 * t + n];
        bv[t]  = ln_b[16 * t + n];
        w1v[t] = lw[64 + 16 * t + n];
    }
    const float bias = lb[0];
    float res[4];
    #pragma unroll
    for (int reg = 0; reg < 4; ++reg) {
        float s  = acc3[0][reg] + acc3[1][reg] + acc3[2][reg] + acc3[3][reg];
        float s2 = acc3[0][reg] * acc3[0][reg] + acc3[1][reg] * acc3[1][reg]
                 + acc3[2][reg] * acc3[2][reg] + acc3[3][reg] * acc3[3][reg];
        s  = rsum16(s);
        s2 = rsum16(s2);
        const float mu  = s * (1.0f / 64.0f);
        const float var = s2 * (1.0f / 64.0f) - mu * mu;
        const float rstd = __builtin_amdgcn_rsqf(var + LN_EPS);
        float dotp = 0.f;
        #pragma unroll
        for (int t = 0; t < 4; ++t) {
            float lnv = (acc3[t][reg] - mu) * rstd * gv[t] + bv[t];
            lnv = fmaxf(lnv, 0.f);
            dotp += lnv * w1v[t];
        }
        dotp = rsum16(dotp);
        // accd[reg] = d0 of this thread's row, valid at n==0 (store lanes)
        res[reg] = __builtin_amdgcn_rcpf(1.0f + __expf(-(dotp + accd[reg] + bias)));
    }
    if (n == 0) {
        float4 o = {res[0], res[1], res[2], res[3]};
        *(float4*)&out[blk * 64 + 16 * w + quad * 4] = o;
    }
}

extern "C" void kernel_launch(void* const* d_in, const int* in_sizes, int n_in,
                              void* d_out, int out_size, void* d_ws, size_t ws_size,
                              hipStream_t stream) {
    const float* fi   = (const float*)d_in[0];
    const float* corr = (const float*)d_in[1];
    const float* g    = (const float*)d_in[2];
    const float* b    = (const float*)d_in[3];
    const float* lw   = (const float*)d_in[4];
    const float* lb   = (const float*)d_in[5];
    float* out        = (float*)d_out;

    const int B = in_sizes[0] / 4096;
    hipLaunchKernelGGL(prep_corr, dim3(1), dim3(256), 0, stream, corr, lw);
    hipLaunchKernelGGL(attn_mfma, dim3(B), dim3(256), 0, stream,
                       fi, g, b, lw, lb, out);
}

// Round 9
// 214.087 us; speedup vs baseline: 1.0119x; 1.0119x over previous
//
#include <hip/hip_runtime.h>
#include <hip/hip_bf16.h>

typedef __attribute__((ext_vector_type(8))) short short8;
typedef __attribute__((ext_vector_type(4))) float floatx4;

constexpr float LN_EPS = 1e-5f;
constexpr float NEG_INF_V = -1e30f;

// 20 KB device-global: pre-swizzled C^T bf16 hi/lo fragments + w0-column tile.
// hi frags 0-7: [0..4095]; lo frags 0-7: [4096..8191];
// tile-4 (w0 col) hi kk=0/1: [8192..9215]; lo kk=0/1: [9216..10239].
// NOTE: frag f holds Ct[16t+n][32kk+8q+e] = corr[k][16t+n]. This exact
// lane->element map serves BOTH as a B-frag (B[k][n]) and as an A-frag
// (A[n][k]) — so M1 can use these as the A-operand with no prep change.
__device__ unsigned short g_wsC[10240];

// ---- bf16 helpers ----
// software RNE (prep kernel only; == HW RNE)
__device__ __forceinline__ unsigned short bf16hi_sw(float x) {
    unsigned int u = __builtin_bit_cast(unsigned int, x);
    u += 0x7FFFu + ((u >> 16) & 1u);
    return (unsigned short)(u >> 16);
}
__device__ __forceinline__ float bf16f(unsigned short h) {
    unsigned int u = ((unsigned int)h) << 16;
    return __builtin_bit_cast(float, u);
}
// HW RNE packed convert via compiler intrinsic. u32: [15:0]=bf16(a), [31:16]=bf16(b).
// R8 LESSON: the inline-asm v_cvt_pk_bf16_f32 form MIS-PACKS on this toolchain
// (absmax 0.37) — keep the intrinsic, which passed R4-R7.
__device__ __forceinline__ unsigned int pk2(float a, float b) {
    float2 f2; f2.x = a; f2.y = b;
    __hip_bfloat162 h2 = __float22bfloat162_rn(f2);
    unsigned int u;
    __builtin_memcpy(&u, &h2, sizeof(u));   // bfloat162 isn't trivially copyable
    return u;
}
// hi/lo split of a pair: lo captures hi's rounding residual (error ~2^-17)
__device__ __forceinline__ void splitpk(float a, float b,
                                        unsigned int& H, unsigned int& L) {
    H = pk2(a, b);
    const float ha = __builtin_bit_cast(float, H << 16);
    const float hb = __builtin_bit_cast(float, H & 0xFFFF0000u);
    L = pk2(a - ha, b - hb);
}

// byte-perm packs: lo16(A)|lo16(B)<<16  /  hi16(A)|hi16(B)<<16
__device__ __forceinline__ unsigned int permlo(unsigned int A, unsigned int B) {
    return __builtin_amdgcn_perm(B, A, 0x05040100u);
}
__device__ __forceinline__ unsigned int permhi(unsigned int A, unsigned int B) {
    return __builtin_amdgcn_perm(B, A, 0x07060302u);
}

// ---- DPP rotate-reduce over 16-lane rows (VALU pipe, zero DS ops) ----
template<int CTRL>
__device__ __forceinline__ float dppadd(float v) {
    int t = __builtin_amdgcn_update_dpp(0, __builtin_bit_cast(int, v),
                                        CTRL, 0xF, 0xF, true);
    return v + __builtin_bit_cast(float, t);
}
template<int CTRL>
__device__ __forceinline__ float dppmax(float v) {
    int t = __builtin_amdgcn_update_dpp(0, __builtin_bit_cast(int, v),
                                        CTRL, 0xF, 0xF, true);
    return fmaxf(v, __builtin_bit_cast(float, t));
}
__device__ __forceinline__ float rsum16(float v) {
    v = dppadd<0x121>(v); v = dppadd<0x122>(v);
    v = dppadd<0x124>(v); v = dppadd<0x128>(v);
    return v;
}
__device__ __forceinline__ float rmax16(float v) {
    v = dppmax<0x121>(v); v = dppmax<0x122>(v);
    v = dppmax<0x124>(v); v = dppmax<0x128>(v);
    return v;
}

// XOR-swizzled 64-col bf16 LDS layout: 16B group g of row r at position g ^ (r&7)
__device__ __forceinline__ int eoff(int r, int c) {
    return r * 64 + ((((c >> 3) ^ r) & 7) << 3) + (c & 7);
}
__device__ __forceinline__ int goff(int r, int g) {
    return r * 64 + (((g ^ r) & 7) << 3);
}
// wave-private 16x64 alpha layout
__device__ __forceinline__ int aoff(int r, int c) {
    return r * 64 + ((((c >> 3) ^ (r >> 2)) & 7) << 3) + (c & 7);
}

// One-shot: C^T fragments + w0-column tile, bf16 hi/lo (layout note above).
__global__ void prep_corr(const float* __restrict__ corr,
                          const float* __restrict__ lw) {
    const int tid  = threadIdx.x;   // 256
    const int lane = tid & 63;
    const int t    = tid >> 6;
    const int nn   = lane & 15;
    const int q    = lane >> 4;
    const int brow = 16 * t + nn;
    #pragma unroll
    for (int kk = 0; kk < 2; ++kk) {
        const int kbase = (kk * 4 + q) * 8;
        short8 H8, L8;
        #pragma unroll
        for (int e = 0; e < 8; ++e) {
            const float v = corr[(kbase + e) * 64 + brow];
            const unsigned short hh = bf16hi_sw(v);
            const unsigned short ll = bf16hi_sw(v - bf16f(hh));
            H8[e] = (short)hh;
            L8[e] = (short)ll;
        }
        const int idx = ((t * 2 + kk) * 64 + lane) * 8;
        *(short8*)&g_wsC[idx]        = H8;
        *(short8*)&g_wsC[4096 + idx] = L8;
    }
    if (t == 0) {   // tile-4: B[k][64+n] = (n==0) ? w0[k] : 0
        #pragma unroll
        for (int kk = 0; kk < 2; ++kk) {
            short8 H8, L8;
            #pragma unroll
            for (int e = 0; e < 8; ++e) {
                const float v = (nn == 0) ? lw[(kk * 4 + q) * 8 + e] : 0.0f;
                const unsigned short hh = bf16hi_sw(v);
                const unsigned short ll = bf16hi_sw(v - bf16f(hh));
                H8[e] = (short)hh;
                L8[e] = (short)ll;
            }
            const int idx = (kk * 64 + lane) * 8;
            *(short8*)&g_wsC[8192 + idx] = H8;
            *(short8*)&g_wsC[9216 + idx] = L8;
        }
    }
}

__global__ __launch_bounds__(256, 4)
void attn_mfma(const float* __restrict__ fi,
               const float* __restrict__ ln_g,
               const float* __restrict__ ln_b,
               const float* __restrict__ lw,
               const float* __restrict__ lb,
               float* __restrict__ out)
{
    // 8+8+8+16 KB = 40960 B -> 4 blocks/CU
    __shared__ __align__(16) unsigned short sFiH[4096], sFiL[4096]; // fi rows h/l
    __shared__ __align__(16) unsigned short sFtH[4096];             // fi^T rows, hi
    // sM: wave-private medium, 2048 shorts/wave.
    // fiC phase: hi rows [0..1023] (eoff(n,e)), lo rows [1024..2047].
    // alpha phase: 16x64 hi in [0..1023] (aoff).
    __shared__ __align__(16) unsigned short sM[8192];

    const int tid  = threadIdx.x;
    const int lane = tid & 63;
    const int w    = tid >> 6;
    const int n    = lane & 15;
    const int quad = lane >> 4;
    const size_t blk = blockIdx.x;
    const int rw   = __builtin_amdgcn_readfirstlane(w);

    unsigned short* mW = &sM[w * 2048];

    // ---- staging: thread owns a 4x4 tile of fi: rows R..R+3, cols C..C+3 ----
    const int C = 4 * n;
    const int R = 4 * (tid >> 4);   // = 16w + 4*quad (wave-private rows)
    {
        const float* fb = fi + blk * 4096;
        float4 v[4];
        #pragma unroll
        for (int i = 0; i < 4; ++i)
            v[i] = *(const float4*)(fb + (R + i) * 64 + C);

        unsigned int H01[4], H23[4], L01[4], L23[4];
        #pragma unroll
        for (int i = 0; i < 4; ++i) {
            splitpk(v[i].x, v[i].y, H01[i], L01[i]);
            splitpk(v[i].z, v[i].w, H23[i], L23[i]);
        }
        #pragma unroll
        for (int i = 0; i < 4; ++i) {
            uint2 H = {H01[i], H23[i]};
            uint2 L = {L01[i], L23[i]};
            *(uint2*)&sFiH[eoff(R + i, C)] = H;
            *(uint2*)&sFiL[eoff(R + i, C)] = L;
        }
        // fi^T rows (hi only): col C+j holds fi[R..R+3][C+j], packed b64
        uint2 t0 = {permlo(H01[0], H01[1]), permlo(H01[2], H01[3])};
        uint2 t1 = {permhi(H01[0], H01[1]), permhi(H01[2], H01[3])};
        uint2 t2 = {permlo(H23[0], H23[1]), permlo(H23[2], H23[3])};
        uint2 t3 = {permhi(H23[0], H23[1]), permhi(H23[2], H23[3])};
        *(uint2*)&sFtH[eoff(C + 0, R)] = t0;
        *(uint2*)&sFtH[eoff(C + 1, R)] = t1;
        *(uint2*)&sFtH[eoff(C + 2, R)] = t2;
        *(uint2*)&sFtH[eoff(C + 3, R)] = t3;
    }

    const int arow = 16 * w + n;

    // ---- M1': fiC^T = C^T @ fi^T (A: g_wsC Ct frags; B: own fi frags Ah/Al).
    // D tile m: lane(n,q) holds fiC[16w+n][16m+4q+j] — fiC ROW is lane-local,
    // so the M2 staging below is 8 contiguous b64 stores, not 32 scalar. ----
    short8 Ah[2], Al[2];
    #pragma unroll
    for (int kk = 0; kk < 2; ++kk) {
        Ah[kk] = *(const short8*)&sFiH[goff(arow, kk * 4 + quad)];
        Al[kk] = *(const short8*)&sFiL[goff(arow, kk * 4 + quad)];
    }
    floatx4 acc1[4];
    #pragma unroll
    for (int m = 0; m < 4; ++m) {
        floatx4 acc = {0.f, 0.f, 0.f, 0.f};
        #pragma unroll
        for (int kk = 0; kk < 2; ++kk) {
            const int f = m * 2 + kk;
            short8 ch = *(const short8*)&g_wsC[(f * 64 + lane) * 8];
            short8 cl = *(const short8*)&g_wsC[4096 + (f * 64 + lane) * 8];
            // 3-pass: Ct_h*fi_h + Ct_l*fi_h + Ct_h*fi_l (same terms as before)
            acc = __builtin_amdgcn_mfma_f32_16x16x32_bf16(ch, Ah[kk], acc, 0, 0, 0);
            acc = __builtin_amdgcn_mfma_f32_16x16x32_bf16(cl, Ah[kk], acc, 0, 0, 0);
            acc = __builtin_amdgcn_mfma_f32_16x16x32_bf16(ch, Al[kk], acc, 0, 0, 0);
        }
        acc1[m] = acc;
    }
    // tile-4: d0[row] = fi[row]·w0 lands in accd[reg] at lanes n==0 (unchanged)
    floatx4 accd = {0.f, 0.f, 0.f, 0.f};
    #pragma unroll
    for (int kk = 0; kk < 2; ++kk) {
        short8 bh = *(const short8*)&g_wsC[8192 + (kk * 64 + lane) * 8];
        short8 bl = *(const short8*)&g_wsC[9216 + (kk * 64 + lane) * 8];
        accd = __builtin_amdgcn_mfma_f32_16x16x32_bf16(Ah[kk], bh, accd, 0, 0, 0);
        accd = __builtin_amdgcn_mfma_f32_16x16x32_bf16(Al[kk], bh, accd, 0, 0, 0);
        accd = __builtin_amdgcn_mfma_f32_16x16x32_bf16(Ah[kk], bl, accd, 0, 0, 0);
    }

    __syncthreads();   // single barrier: sFi/sFt staging visible to all waves

    // ---- stage fiC row (lane-local) into medium: 4 hi + 4 lo b64 stores ----
    #pragma unroll
    for (int m = 0; m < 4; ++m) {
        unsigned int H01, L01, H23, L23;
        splitpk(acc1[m][0], acc1[m][1], H01, L01);   // e = 16m+4q+0,1
        splitpk(acc1[m][2], acc1[m][3], H23, L23);   // e = 16m+4q+2,3
        const int e = 16 * m + 4 * quad;
        uint2 H = {H01, H23};
        uint2 L = {L01, L23};
        *(uint2*)&mW[eoff(n, e)]        = H;
        *(uint2*)&mW[1024 + eoff(n, e)] = L;
    }
    // A-frags for M2: fiC[arow][32kk+8q..+7], b128 reads
    short8 PAh[2], PAl[2];
    #pragma unroll
    for (int kk = 0; kk < 2; ++kk) {
        PAh[kk] = *(const short8*)&mW[goff(n, kk * 4 + quad)];
        PAl[kk] = *(const short8*)&mW[1024 + goff(n, kk * 4 + quad)];
    }

    // ---- M2: beta = fiC @ fi^T (A: own fiC rows; B: sFi rows, all waves) ----
    floatx4 acc2[4];
    #pragma unroll
    for (int t = 0; t < 4; ++t) acc2[t] = floatx4{0.f, 0.f, 0.f, 0.f};
    #pragma unroll
    for (int kh = 0; kh < 2; ++kh) {
        #pragma unroll
        for (int t = 0; t < 4; ++t) {
            const int brow = 16 * t + n;
            short8 bh = *(const short8*)&sFiH[goff(brow, kh * 4 + quad)];
            short8 bl = *(const short8*)&sFiL[goff(brow, kh * 4 + quad)];
            acc2[t] = __builtin_amdgcn_mfma_f32_16x16x32_bf16(PAh[kh], bh, acc2[t], 0, 0, 0);
            acc2[t] = __builtin_amdgcn_mfma_f32_16x16x32_bf16(PAl[kh], bh, acc2[t], 0, 0, 0);
            acc2[t] = __builtin_amdgcn_mfma_f32_16x16x32_bf16(PAh[kh], bl, acc2[t], 0, 0, 0);
        }
    }

    // ---- masked softmax, UNNORMALIZED (LN is scale-invariant) ----
    // diag col == row  <=>  t == w (wave-uniform) && n == 4*quad+reg
    #pragma unroll
    for (int reg = 0; reg < 4; ++reg) {
        float x[4];
        #pragma unroll
        for (int t = 0; t < 4; ++t) x[t] = acc2[t][reg];
        #pragma unroll
        for (int t = 0; t < 4; ++t)
            if (t == rw)    // uniform branch: one cndmask survives
                x[t] = (n == 4 * quad + reg) ? NEG_INF_V : x[t];
        float m = fmaxf(fmaxf(x[0], x[1]), fmaxf(x[2], x[3]));
        m = rmax16(m);
        #pragma unroll
        for (int t = 0; t < 4; ++t) x[t] = __expf(x[t] - m);   // <= 1
        const unsigned int A01 = pk2(x[0], x[1]);
        const unsigned int A23 = pk2(x[2], x[3]);
        const int lr = quad * 4 + reg;          // local row within wave
        mW[aoff(lr, 0 + n)]  = (unsigned short)A01;
        mW[aoff(lr, 16 + n)] = (unsigned short)(A01 >> 16);
        mW[aoff(lr, 32 + n)] = (unsigned short)A23;
        mW[aoff(lr, 48 + n)] = (unsigned short)(A23 >> 16);
    }

    // ---- M3: vi_unnorm = exp(beta-m) @ fi (hi-only single pass) ----
    short8 AAh[2];
    #pragma unroll
    for (int kk = 0; kk < 2; ++kk)
        AAh[kk] = *(const short8*)&mW[aoff(n, (kk * 4 + quad) * 8)];
    floatx4 acc3[4];
    #pragma unroll
    for (int t = 0; t < 4; ++t) {
        floatx4 acc = {0.f, 0.f, 0.f, 0.f};
        const int brow = 16 * t + n;
        #pragma unroll
        for (int kk = 0; kk < 2; ++kk) {
            short8 bh = *(const short8*)&sFtH[goff(brow, kk * 4 + quad)];
            acc = __builtin_amdgcn_mfma_f32_16x16x32_bf16(AAh[kk], bh, acc, 0, 0, 0);
        }
        acc3[t] = acc;
    }

    // ---- LN + ReLU + final dot + sigmoid ----
    float gv[4], bv[4], w1v[4];
    #pragma unroll
    for (int t = 0; t < 4; ++t) {
        gv[t]  = ln_g[16 * t + n];
        bv[t]  = ln_b[16 * t + n];
        w1v[t] = lw[64 + 16 * t + n];
    }
    const float bias = lb[0];
    float res[4];
    #pragma unroll
    for (int reg = 0; reg < 4; ++reg) {
        float s  = acc3[0][reg] + acc3[1][reg] + acc3[2][reg] + acc3[3][reg];
        float s2 = acc3[0][reg] * acc3[0][reg] + acc3[1][reg] * acc3[1][reg]
                 + acc3[2][reg] * acc3[2][reg] + acc3[3][reg] * acc3[3][reg];
        s  = rsum16(s);
        s2 = rsum16(s2);
        const float mu  = s * (1.0f / 64.0f);
        const float var = s2 * (1.0f / 64.0f) - mu * mu;
        const float rstd = __builtin_amdgcn_rsqf(var + LN_EPS);
        float dotp = 0.f;
        #pragma unroll
        for (int t = 0; t < 4; ++t) {
            float lnv = (acc3[t][reg] - mu) * rstd * gv[t] + bv[t];
            lnv = fmaxf(lnv, 0.f);
            dotp += lnv * w1v[t];
        }
        dotp = rsum16(dotp);
        // accd[reg] = d0 of this thread's row, valid at n==0 (store lanes)
        res[reg] = __builtin_amdgcn_rcpf(1.0f + __expf(-(dotp + accd[reg] + bias)));
    }
    if (n == 0) {
        float4 o = {res[0], res[1], res[2], res[3]};
        *(float4*)&out[blk * 64 + 16 * w + quad * 4] = o;
    }
}

extern "C" void kernel_launch(void* const* d_in, const int* in_sizes, int n_in,
                              void* d_out, int out_size, void* d_ws, size_t ws_size,
                              hipStream_t stream) {
    const float* fi   = (const float*)d_in[0];
    const float* corr = (const float*)d_in[1];
    const float* g    = (const float*)d_in[2];
    const float* b    = (const float*)d_in[3];
    const float* lw   = (const float*)d_in[4];
    const float* lb   = (const float*)d_in[5];
    float* out        = (float*)d_out;

    const int B = in_sizes[0] / 4096;
    hipLaunchKernelGGL(prep_corr, dim3(1), dim3(256), 0, stream, corr, lw);
    hipLaunchKernelGGL(attn_mfma, dim3(B), dim3(256), 0, stream,
                       fi, g, b, lw, lb, out);
}